// Round 1
// baseline (38.929 us; speedup 1.0000x reference)
//
#include <hip/hip_runtime.h>
#include <math.h>

#define HIDDEN 768
#define EPS 1e-4f

// Fill entire output with 1+EPS (covers diagonal; off-diagonal overwritten later).
__global__ void fill_ones_kernel(float* __restrict__ out, int n) {
    int t = blockIdx.x * blockDim.x + threadIdx.x;
    if (t < n) out[t] = 1.0f + EPS;
}

// One wave (64 lanes) per row: dot(pooled[p], W) -> sigmoid -> scatter.
__global__ void pair_scores_kernel(const float* __restrict__ pooled,
                                   const float* __restrict__ W,
                                   const float* __restrict__ bias,
                                   const int* __restrict__ pairs,
                                   const int* __restrict__ length_ptr,
                                   float* __restrict__ out,
                                   int P) {
    const int lane  = threadIdx.x & 63;
    const int wave  = (blockIdx.x * blockDim.x + threadIdx.x) >> 6;
    const int nwave = (gridDim.x * blockDim.x) >> 6;

    const int L   = length_ptr[0];        // 32
    const int ppp = L * (L - 1);          // 992
    const int LL  = L * L;                // 1024
    const float bval = bias[0];

    const float4* __restrict__ wp = reinterpret_cast<const float4*>(W);
    // Preload W fragment once per wave (same for every row).
    float4 w0 = wp[lane];
    float4 w1 = wp[lane + 64];
    float4 w2 = wp[lane + 128];

    for (int p = wave; p < P; p += nwave) {
        const float4* __restrict__ rowp =
            reinterpret_cast<const float4*>(pooled + (size_t)p * HIDDEN);
        float4 a0 = rowp[lane];
        float4 a1 = rowp[lane + 64];
        float4 a2 = rowp[lane + 128];

        float sum = a0.x * w0.x + a0.y * w0.y + a0.z * w0.z + a0.w * w0.w;
        sum      += a1.x * w1.x + a1.y * w1.y + a1.z * w1.z + a1.w * w1.w;
        sum      += a2.x * w2.x + a2.y * w2.y + a2.z * w2.z + a2.w * w2.w;

        // 64-lane butterfly reduce.
        #pragma unroll
        for (int off = 32; off >= 1; off >>= 1)
            sum += __shfl_xor(sum, off, 64);

        if (lane == 0) {
            float s = 1.0f / (1.0f + expf(-(sum + bval)));
            int bidx = p / ppp;
            int r = pairs[2 * p];
            int c = pairs[2 * p + 1];
            out[(size_t)bidx * LL + r * L + c] = s + EPS;
        }
    }
}

extern "C" void kernel_launch(void* const* d_in, const int* in_sizes, int n_in,
                              void* d_out, int out_size, void* d_ws, size_t ws_size,
                              hipStream_t stream) {
    const float* pooled = (const float*)d_in[0];
    const float* W      = (const float*)d_in[1];
    const float* bias   = (const float*)d_in[2];
    const int*   pairs  = (const int*)d_in[3];
    const int*   lenp   = (const int*)d_in[5];   // `length` device scalar
    float* out = (float*)d_out;

    const int P = in_sizes[0] / HIDDEN;          // 63488 rows

    // 1) init all entries to 1+EPS
    {
        int threads = 256;
        int blocks = (out_size + threads - 1) / threads;
        fill_ones_kernel<<<blocks, threads, 0, stream>>>(out, out_size);
    }

    // 2) per-row sigmoid(dot) scatter; one wave per row, grid capped at 2048 blocks
    {
        int threads = 256;                        // 4 waves/block
        int waves_needed = P;
        int blocks = (waves_needed + 3) / 4;
        if (blocks > 2048) blocks = 2048;
        pair_scores_kernel<<<blocks, threads, 0, stream>>>(
            pooled, W, bias, pairs, lenp, out, P);
    }
}

// Round 2
// 34.269 us; speedup vs baseline: 1.1360x; 1.1360x over previous
//
#include <hip/hip_runtime.h>
#include <math.h>

#define HIDDEN 768
#define EPS 1e-4f

// One wave (64 lanes) per row: dot(pooled[p], W) -> sigmoid -> scatter.
// Waves p < B*L also write one diagonal element (1+EPS); diagonal is never
// touched by the scatter (pairs always have r != c), so no race.
__global__ void pair_scores_kernel(const float* __restrict__ pooled,
                                   const float* __restrict__ W,
                                   const float* __restrict__ bias,
                                   const int* __restrict__ pairs,
                                   const int* __restrict__ length_ptr,
                                   float* __restrict__ out,
                                   int P) {
    const int lane  = threadIdx.x & 63;
    const int wave  = (blockIdx.x * blockDim.x + threadIdx.x) >> 6;
    const int nwave = (gridDim.x * blockDim.x) >> 6;

    const int L   = length_ptr[0];        // 32
    const int ppp = L * (L - 1);          // 992
    const int LL  = L * L;                // 1024
    const int nDiag = (P / ppp) * L;      // B * L = 2048
    const float bval = bias[0];

    const float4* __restrict__ wp = reinterpret_cast<const float4*>(W);
    // Preload W fragment once per wave (same for every row).
    float4 w0 = wp[lane];
    float4 w1 = wp[lane + 64];
    float4 w2 = wp[lane + 128];

    for (int p = wave; p < P; p += nwave) {
        const float4* __restrict__ rowp =
            reinterpret_cast<const float4*>(pooled + (size_t)p * HIDDEN);
        float4 a0 = rowp[lane];
        float4 a1 = rowp[lane + 64];
        float4 a2 = rowp[lane + 128];

        float sum = a0.x * w0.x + a0.y * w0.y + a0.z * w0.z + a0.w * w0.w;
        sum      += a1.x * w1.x + a1.y * w1.y + a1.z * w1.z + a1.w * w1.w;
        sum      += a2.x * w2.x + a2.y * w2.y + a2.z * w2.z + a2.w * w2.w;

        // 64-lane butterfly reduce.
        #pragma unroll
        for (int off = 32; off >= 1; off >>= 1)
            sum += __shfl_xor(sum, off, 64);

        if (lane == 0) {
            float s = 1.0f / (1.0f + expf(-(sum + bval)));
            int bidx = p / ppp;
            int r = pairs[2 * p];
            int c = pairs[2 * p + 1];
            out[(size_t)bidx * LL + r * L + c] = s + EPS;
        } else if (lane == 1 && p < nDiag) {
            // diagonal element (d / L, d % L, d % L) for d = p
            int b = p / L;
            int d = p - b * L;
            out[(size_t)b * LL + d * L + d] = 1.0f + EPS;
        }
    }
}

extern "C" void kernel_launch(void* const* d_in, const int* in_sizes, int n_in,
                              void* d_out, int out_size, void* d_ws, size_t ws_size,
                              hipStream_t stream) {
    const float* pooled = (const float*)d_in[0];
    const float* W      = (const float*)d_in[1];
    const float* bias   = (const float*)d_in[2];
    const int*   pairs  = (const int*)d_in[3];
    const int*   lenp   = (const int*)d_in[5];   // `length` device scalar
    float* out = (float*)d_out;

    const int P = in_sizes[0] / HIDDEN;          // 63488 rows

    // One wave per row, grid capped at 2048 blocks (8192 waves = 32/CU).
    int threads = 256;                            // 4 waves/block
    int blocks = (P + 3) / 4;
    if (blocks > 2048) blocks = 2048;
    pair_scores_kernel<<<blocks, threads, 0, stream>>>(
        pooled, W, bias, pairs, lenp, out, P);
}